// Round 6
// baseline (154.376 us; speedup 1.0000x reference)
//
#include <hip/hip_runtime.h>

namespace {

constexpr int BATCH = 8192;
constexpr int EMB   = 128;
constexpr int HID   = 512;
constexpr int NMOD  = 64;
constexpr int CAP   = 256;   // 16 slots x 16 rows; Bin(8192,1/64) max ~170
constexpr int CSTR  = 16;    // counter stride in ints = 64B (one cacheline)
constexpr float WB  = 1.0f / (7.0f * 0.5f);  // 2/7

// ws layout (float offsets)
constexpr size_t OFF_WT  = 0;                  // 64*128*128 [k][o]
constexpr size_t OFF_X0  = 1048576;            // 8192*128
constexpr size_t OFF_X1  = 2097152;            // 8192*128
constexpr size_t OFF_W1T = 3145728;            // 128*512  [k][col]
constexpr size_t OFF_W2T = 3211264;            // 512*64   [k][col]
constexpr size_t OFF_CNT = 3244032;            // 192*CSTR ints (zeroed)
constexpr size_t OFF_BKT = OFF_CNT + 192 * CSTR;  // 3*64*CAP ints
// end ~13.2 MB << ws_size

// ---- prep: weight transposes + bucket scatter (one kernel, disjoint bx) ---
// bx 0..127: W_mods transpose (2 blocks/module); 128..135: W1T; 136..143: W2T;
// 144..239: bucket scatter.
__global__ __launch_bounds__(256) void k_prep(const float* __restrict__ Wm,
                                              const float* __restrict__ W1,
                                              const float* __restrict__ W2,
                                              const int* __restrict__ mids,
                                              float* __restrict__ ws) {
  __shared__ float t[64 * 129];
  const int bx = blockIdx.x;
  const int tid = threadIdx.x;
  if (bx < 128) {  // module m = bx>>1, row-half h = bx&1
    const int m = bx >> 1, h = bx & 1;
    const float* src = Wm + (size_t)m * 16384 + (size_t)h * 64 * 128;
    float* dst = ws + OFF_WT + (size_t)m * 16384;
    for (int e = tid; e < 64 * 32; e += 256) {
      const int o = e >> 5, i4 = e & 31;
      const float4 v = *(const float4*)&src[(size_t)o * 128 + 4 * i4];
      float* d = &t[o * 129 + 4 * i4];
      d[0] = v.x; d[1] = v.y; d[2] = v.z; d[3] = v.w;
    }
    __syncthreads();
    for (int e = tid; e < 128 * 16; e += 256) {
      const int i = e >> 4, o4 = e & 15;
      float4 u;
      u.x = t[(4 * o4 + 0) * 129 + i];
      u.y = t[(4 * o4 + 1) * 129 + i];
      u.z = t[(4 * o4 + 2) * 129 + i];
      u.w = t[(4 * o4 + 3) * 129 + i];
      *(float4*)&dst[(size_t)i * 128 + h * 64 + 4 * o4] = u;
    }
  } else if (bx < 136) {  // W1 [512][128] -> W1T [128][512]
    const int j = bx - 128;
    for (int e = tid; e < 64 * 32; e += 256) {
      const int r = e >> 5, i4 = e & 31;
      const float4 v = *(const float4*)&W1[(size_t)(j * 64 + r) * 128 + 4 * i4];
      float* d = &t[r * 129 + 4 * i4];
      d[0] = v.x; d[1] = v.y; d[2] = v.z; d[3] = v.w;
    }
    __syncthreads();
    float* W1T = ws + OFF_W1T;
    for (int e = tid; e < 128 * 16; e += 256) {
      const int i = e >> 4, r4 = e & 15;
      float4 v;
      v.x = t[(4 * r4 + 0) * 129 + i];
      v.y = t[(4 * r4 + 1) * 129 + i];
      v.z = t[(4 * r4 + 2) * 129 + i];
      v.w = t[(4 * r4 + 3) * 129 + i];
      *(float4*)&W1T[(size_t)i * 512 + j * 64 + 4 * r4] = v;
    }
  } else if (bx < 144) {  // W2 [64][512] -> W2T [512][64]
    const int j = bx - 136;
    float* t2 = t;  // [64][65]
    for (int e = tid; e < 64 * 16; e += 256) {
      const int o = e >> 4, k4 = e & 15;
      const float4 v = *(const float4*)&W2[(size_t)o * 512 + j * 64 + 4 * k4];
      float* d = &t2[o * 65 + 4 * k4];
      d[0] = v.x; d[1] = v.y; d[2] = v.z; d[3] = v.w;
    }
    __syncthreads();
    float* W2T = ws + OFF_W2T;
    for (int e = tid; e < 64 * 16; e += 256) {
      const int k = e >> 4, o4 = e & 15;
      float4 v;
      v.x = t2[(4 * o4 + 0) * 65 + k];
      v.y = t2[(4 * o4 + 1) * 65 + k];
      v.z = t2[(4 * o4 + 2) * 65 + k];
      v.w = t2[(4 * o4 + 3) * 65 + k];
      *(float4*)&W2T[(size_t)(j * 64 + k) * 64 + 4 * o4] = v;
    }
  } else {  // bucket scatter; padded counters (1 per 64B cacheline)
    const int idx = (bx - 144) * 256 + tid;
    if (idx < BATCH * 3) {
      const int b = idx / 3, h = idx - b * 3;
      const int m = mids[idx];
      int* cnt = (int*)(ws + OFF_CNT);
      int* bkt = (int*)(ws + OFF_BKT);
      const int pos = atomicAdd(&cnt[(h * NMOD + m) * CSTR], 1);
      bkt[(h * NMOD + m) * CAP + pos] = b;
    }
  }
}

// ---- hop: per-module 16-row x 128-col tile, W streamed from L2 ------------
template <int HOP>
__global__ __launch_bounds__(256) void k_hop(const float* __restrict__ E,
                                             const int* __restrict__ eids,
                                             float* __restrict__ ws) {
  const int m = blockIdx.x >> 4, sl = blockIdx.x & 15;
  const int cn = ((const int*)(ws + OFF_CNT))[(HOP * NMOD + m) * CSTR];
  const int r0 = sl * 16;
  if (r0 >= cn) return;
  const int nr = min(16, cn - r0);

  __shared__ float xs[16 * 129];
  __shared__ int rows[16];
  const int tid = threadIdx.x;
  const float* Wk = ws + OFF_WT + (size_t)m * 16384;  // [k][o]
  const int* bkt = (const int*)(ws + OFF_BKT) + (HOP * NMOD + m) * CAP + r0;
  const float* Xprev = ws + (HOP == 1 ? OFF_X0 : OFF_X1);
  float* Xnext = ws + (HOP == 1 ? OFF_X1 : OFF_X0);

  if (tid < nr) rows[tid] = bkt[tid];
  __syncthreads();
  for (int e = tid; e < 16 * 32; e += 256) {
    const int row = e >> 5, i4 = e & 31;
    if (row < nr) {
      const int b = rows[row];
      const float* src = (HOP == 0) ? (E + (size_t)eids[b * 4] * EMB)
                                    : (Xprev + (size_t)b * EMB);
      *(float4*)&xs[row * 129 + 4 * i4] = *(const float4*)&src[4 * i4];
    }
  }
  __syncthreads();

  const int r = tid >> 4, tc = tid & 15;  // one row, 8 cols per thread
  float a0 = 0.f, a1 = 0.f, a2 = 0.f, a3 = 0.f;
  float a4 = 0.f, a5 = 0.f, a6 = 0.f, a7 = 0.f;
#pragma unroll 4
  for (int k = 0; k < 128; ++k) {
    const float4 w0 = *(const float4*)&Wk[(size_t)k * 128 + 4 * tc];
    const float4 w1 = *(const float4*)&Wk[(size_t)k * 128 + 64 + 4 * tc];
    const float x = xs[r * 129 + k];
    a0 = fmaf(x, w0.x, a0); a1 = fmaf(x, w0.y, a1);
    a2 = fmaf(x, w0.z, a2); a3 = fmaf(x, w0.w, a3);
    a4 = fmaf(x, w1.x, a4); a5 = fmaf(x, w1.y, a5);
    a6 = fmaf(x, w1.z, a6); a7 = fmaf(x, w1.w, a7);
  }

  if (r < nr) {
    const int b = rows[r];
    const float* bp = E + (size_t)eids[b * 4 + HOP + 1] * EMB;
    const float4 bias0 = *(const float4*)&bp[4 * tc];
    const float4 bias1 = *(const float4*)&bp[64 + 4 * tc];
    float4 o0, o1;
    o0.x = fmaxf(a0 + bias0.x, 0.f);
    o0.y = fmaxf(a1 + bias0.y, 0.f);
    o0.z = fmaxf(a2 + bias0.z, 0.f);
    o0.w = fmaxf(a3 + bias0.w, 0.f);
    o1.x = fmaxf(a4 + bias1.x, 0.f);
    o1.y = fmaxf(a5 + bias1.y, 0.f);
    o1.z = fmaxf(a6 + bias1.z, 0.f);
    o1.w = fmaxf(a7 + bias1.w, 0.f);
    if (HOP == 2) {
      o0.x = (1.f - WB) * bias0.x + WB * o0.x;
      o0.y = (1.f - WB) * bias0.y + WB * o0.y;
      o0.z = (1.f - WB) * bias0.z + WB * o0.z;
      o0.w = (1.f - WB) * bias0.w + WB * o0.w;
      o1.x = (1.f - WB) * bias1.x + WB * o1.x;
      o1.y = (1.f - WB) * bias1.y + WB * o1.y;
      o1.z = (1.f - WB) * bias1.z + WB * o1.z;
      o1.w = (1.f - WB) * bias1.w + WB * o1.w;
    }
    *(float4*)&Xnext[(size_t)b * EMB + 4 * tc] = o0;
    *(float4*)&Xnext[(size_t)b * EMB + 64 + 4 * tc] = o1;
  }
}

// ---- fused MLP: 16 rows/block; H tile lives in LDS ------------------------
constexpr int HS = 516;  // H LDS stride (2-way max aliasing = free)
__global__ __launch_bounds__(256) void k_mlp(const float* __restrict__ b1,
                                             const float* __restrict__ b2,
                                             float* __restrict__ ws,
                                             float* __restrict__ out) {
  __shared__ float xs[16 * 129];    //  8.25 KB
  __shared__ float hs[16 * HS];     // 33.0 KB
  __shared__ float part[4 * 1024];  // 16.4 KB
  const int tid = threadIdx.x;
  const int row0 = blockIdx.x * 16;
  const float* X = ws + OFF_X0;
  const float* W1T = ws + OFF_W1T;
  const float* W2T = ws + OFF_W2T;

  for (int e = tid; e < 16 * 32; e += 256) {
    const int row = e >> 5, i4 = e & 31;
    *(float4*)&xs[row * 129 + 4 * i4] =
        *(const float4*)&X[(size_t)(row0 + row) * EMB + 4 * i4];
  }
  __syncthreads();

  const int wv = tid >> 6, ln = tid & 63;
#pragma unroll
  for (int pass = 0; pass < 2; ++pass) {
    float acc[4][4] = {};
    const float* Wp = W1T + pass * 256 + 4 * ln;
#pragma unroll 4
    for (int k = 0; k < 128; ++k) {
      const float4 w = *(const float4*)&Wp[(size_t)k * 512];
      const float a0 = xs[(wv * 4 + 0) * 129 + k];
      const float a1 = xs[(wv * 4 + 1) * 129 + k];
      const float a2 = xs[(wv * 4 + 2) * 129 + k];
      const float a3 = xs[(wv * 4 + 3) * 129 + k];
      acc[0][0] = fmaf(a0, w.x, acc[0][0]); acc[0][1] = fmaf(a0, w.y, acc[0][1]);
      acc[0][2] = fmaf(a0, w.z, acc[0][2]); acc[0][3] = fmaf(a0, w.w, acc[0][3]);
      acc[1][0] = fmaf(a1, w.x, acc[1][0]); acc[1][1] = fmaf(a1, w.y, acc[1][1]);
      acc[1][2] = fmaf(a1, w.z, acc[1][2]); acc[1][3] = fmaf(a1, w.w, acc[1][3]);
      acc[2][0] = fmaf(a2, w.x, acc[2][0]); acc[2][1] = fmaf(a2, w.y, acc[2][1]);
      acc[2][2] = fmaf(a2, w.z, acc[2][2]); acc[2][3] = fmaf(a2, w.w, acc[2][3]);
      acc[3][0] = fmaf(a3, w.x, acc[3][0]); acc[3][1] = fmaf(a3, w.y, acc[3][1]);
      acc[3][2] = fmaf(a3, w.z, acc[3][2]); acc[3][3] = fmaf(a3, w.w, acc[3][3]);
    }
    const float4 bb = *(const float4*)&b1[pass * 256 + 4 * ln];
#pragma unroll
    for (int r = 0; r < 4; ++r) {
      float4 o;
      o.x = fmaxf(acc[r][0] + bb.x, 0.f);
      o.y = fmaxf(acc[r][1] + bb.y, 0.f);
      o.z = fmaxf(acc[r][2] + bb.z, 0.f);
      o.w = fmaxf(acc[r][3] + bb.w, 0.f);
      *(float4*)&hs[(wv * 4 + r) * HS + pass * 256 + 4 * ln] = o;
    }
  }
  __syncthreads();

  // phase B: wave wv handles k in [wv*128, wv*128+128)
  const int lr = ln >> 4, lc = ln & 15;
  float acc2[4][4] = {};
  const float* W2p = W2T + (size_t)wv * 128 * 64 + 4 * lc;
#pragma unroll 4
  for (int kk = 0; kk < 128; ++kk) {
    const int k = wv * 128 + kk;
    const float4 w = *(const float4*)&W2p[(size_t)kk * 64];
    const float a0 = hs[(lr * 4 + 0) * HS + k];
    const float a1 = hs[(lr * 4 + 1) * HS + k];
    const float a2 = hs[(lr * 4 + 2) * HS + k];
    const float a3 = hs[(lr * 4 + 3) * HS + k];
    acc2[0][0] = fmaf(a0, w.x, acc2[0][0]); acc2[0][1] = fmaf(a0, w.y, acc2[0][1]);
    acc2[0][2] = fmaf(a0, w.z, acc2[0][2]); acc2[0][3] = fmaf(a0, w.w, acc2[0][3]);
    acc2[1][0] = fmaf(a1, w.x, acc2[1][0]); acc2[1][1] = fmaf(a1, w.y, acc2[1][1]);
    acc2[1][2] = fmaf(a1, w.z, acc2[1][2]); acc2[1][3] = fmaf(a1, w.w, acc2[1][3]);
    acc2[2][0] = fmaf(a2, w.x, acc2[2][0]); acc2[2][1] = fmaf(a2, w.y, acc2[2][1]);
    acc2[2][2] = fmaf(a2, w.z, acc2[2][2]); acc2[2][3] = fmaf(a2, w.w, acc2[2][3]);
    acc2[3][0] = fmaf(a3, w.x, acc2[3][0]); acc2[3][1] = fmaf(a3, w.y, acc2[3][1]);
    acc2[3][2] = fmaf(a3, w.z, acc2[3][2]); acc2[3][3] = fmaf(a3, w.w, acc2[3][3]);
  }
#pragma unroll
  for (int r = 0; r < 4; ++r) {
    float4 pv;
    pv.x = acc2[r][0]; pv.y = acc2[r][1]; pv.z = acc2[r][2]; pv.w = acc2[r][3];
    *(float4*)&part[wv * 1024 + (lr * 4 + r) * 64 + 4 * lc] = pv;
  }
  __syncthreads();

  {
    const int r = tid >> 4, cf = tid & 15;
    float4 s = *(const float4*)&part[r * 64 + 4 * cf];
#pragma unroll
    for (int w = 1; w < 4; ++w) {
      const float4 t = *(const float4*)&part[w * 1024 + r * 64 + 4 * cf];
      s.x += t.x; s.y += t.y; s.z += t.z; s.w += t.w;
    }
    const float4 bb = *(const float4*)&b2[4 * cf];
    float4 o;
    o.x = s.x + bb.x; o.y = s.y + bb.y; o.z = s.z + bb.z; o.w = s.w + bb.w;
    *(float4*)&out[(size_t)(row0 + r) * 64 + 4 * cf] = o;
  }
}

}  // namespace

extern "C" void kernel_launch(void* const* d_in, const int* in_sizes, int n_in,
                              void* d_out, int out_size, void* d_ws,
                              size_t ws_size, hipStream_t stream) {
  const float* E  = (const float*)d_in[0];
  const float* Wm = (const float*)d_in[1];
  const float* W1 = (const float*)d_in[2];
  const float* b1 = (const float*)d_in[3];
  const float* W2 = (const float*)d_in[4];
  const float* b2 = (const float*)d_in[5];
  const int* eids = (const int*)d_in[6];
  const int* mids = (const int*)d_in[7];
  float* out = (float*)d_out;
  float* ws = (float*)d_ws;

  (void)hipMemsetAsync((char*)d_ws + OFF_CNT * sizeof(float), 0,
                       192 * CSTR * sizeof(int), stream);
  k_prep<<<dim3(240), dim3(256), 0, stream>>>(Wm, W1, W2, mids, ws);
  k_hop<0><<<dim3(1024), dim3(256), 0, stream>>>(E, eids, ws);
  k_hop<1><<<dim3(1024), dim3(256), 0, stream>>>(E, eids, ws);
  k_hop<2><<<dim3(1024), dim3(256), 0, stream>>>(E, eids, ws);
  k_mlp<<<dim3(512), dim3(256), 0, stream>>>(b1, b2, ws, out);
}

// Round 7
// 105.790 us; speedup vs baseline: 1.4593x; 1.4593x over previous
//
#include <hip/hip_runtime.h>

namespace {

constexpr int BATCH = 8192;
constexpr int EMB   = 128;
constexpr int HID   = 512;
constexpr int NMOD  = 64;
constexpr int CAP   = 256;   // 4 slots x 64 rows; Bin(8192,1/64) max ~170
constexpr int CSTR  = 16;    // counter stride in ints = 64B
constexpr float WB  = 1.0f / (7.0f * 0.5f);  // 2/7

// ws layout (float offsets)
constexpr size_t OFF_WT  = 0;                  // 64*128*128 [k][o]
constexpr size_t OFF_X0  = 1048576;            // 8192*128
constexpr size_t OFF_X1  = 2097152;            // 8192*128
constexpr size_t OFF_W1T = 3145728;            // 128*512  [k][col]
constexpr size_t OFF_W2T = 3211264;            // 512*64   [k][col]
constexpr size_t OFF_CNT = 3244032;            // 192*CSTR ints (zeroed)
constexpr size_t OFF_BKT = OFF_CNT + 192 * CSTR;  // 3*64*CAP ints
// end ~13.2 MB << ws_size

// ---- prep: weight transposes + bucket scatter (one kernel, disjoint bx) ---
__global__ __launch_bounds__(256) void k_prep(const float* __restrict__ Wm,
                                              const float* __restrict__ W1,
                                              const float* __restrict__ W2,
                                              const int* __restrict__ mids,
                                              float* __restrict__ ws) {
  __shared__ float t[64 * 129];
  const int bx = blockIdx.x;
  const int tid = threadIdx.x;
  if (bx < 128) {  // module m = bx>>1, row-half h = bx&1
    const int m = bx >> 1, h = bx & 1;
    const float* src = Wm + (size_t)m * 16384 + (size_t)h * 64 * 128;
    float* dst = ws + OFF_WT + (size_t)m * 16384;
    for (int e = tid; e < 64 * 32; e += 256) {
      const int o = e >> 5, i4 = e & 31;
      const float4 v = *(const float4*)&src[(size_t)o * 128 + 4 * i4];
      float* d = &t[o * 129 + 4 * i4];
      d[0] = v.x; d[1] = v.y; d[2] = v.z; d[3] = v.w;
    }
    __syncthreads();
    for (int e = tid; e < 128 * 16; e += 256) {
      const int i = e >> 4, o4 = e & 15;
      float4 u;
      u.x = t[(4 * o4 + 0) * 129 + i];
      u.y = t[(4 * o4 + 1) * 129 + i];
      u.z = t[(4 * o4 + 2) * 129 + i];
      u.w = t[(4 * o4 + 3) * 129 + i];
      *(float4*)&dst[(size_t)i * 128 + h * 64 + 4 * o4] = u;
    }
  } else if (bx < 136) {  // W1 [512][128] -> W1T [128][512]
    const int j = bx - 128;
    for (int e = tid; e < 64 * 32; e += 256) {
      const int r = e >> 5, i4 = e & 31;
      const float4 v = *(const float4*)&W1[(size_t)(j * 64 + r) * 128 + 4 * i4];
      float* d = &t[r * 129 + 4 * i4];
      d[0] = v.x; d[1] = v.y; d[2] = v.z; d[3] = v.w;
    }
    __syncthreads();
    float* W1T = ws + OFF_W1T;
    for (int e = tid; e < 128 * 16; e += 256) {
      const int i = e >> 4, r4 = e & 15;
      float4 v;
      v.x = t[(4 * r4 + 0) * 129 + i];
      v.y = t[(4 * r4 + 1) * 129 + i];
      v.z = t[(4 * r4 + 2) * 129 + i];
      v.w = t[(4 * r4 + 3) * 129 + i];
      *(float4*)&W1T[(size_t)i * 512 + j * 64 + 4 * r4] = v;
    }
  } else if (bx < 144) {  // W2 [64][512] -> W2T [512][64]
    const int j = bx - 136;
    float* t2 = t;  // [64][65]
    for (int e = tid; e < 64 * 16; e += 256) {
      const int o = e >> 4, k4 = e & 15;
      const float4 v = *(const float4*)&W2[(size_t)o * 512 + j * 64 + 4 * k4];
      float* d = &t2[o * 65 + 4 * k4];
      d[0] = v.x; d[1] = v.y; d[2] = v.z; d[3] = v.w;
    }
    __syncthreads();
    float* W2T = ws + OFF_W2T;
    for (int e = tid; e < 64 * 16; e += 256) {
      const int k = e >> 4, o4 = e & 15;
      float4 v;
      v.x = t2[(4 * o4 + 0) * 65 + k];
      v.y = t2[(4 * o4 + 1) * 65 + k];
      v.z = t2[(4 * o4 + 2) * 65 + k];
      v.w = t2[(4 * o4 + 3) * 65 + k];
      *(float4*)&W2T[(size_t)(j * 64 + k) * 64 + 4 * o4] = v;
    }
  } else {  // bucket scatter; padded counters
    const int idx = (bx - 144) * 256 + tid;
    if (idx < BATCH * 3) {
      const int b = idx / 3, h = idx - b * 3;
      const int m = mids[idx];
      int* cnt = (int*)(ws + OFF_CNT);
      int* bkt = (int*)(ws + OFF_BKT);
      const int pos = atomicAdd(&cnt[(h * NMOD + m) * CSTR], 1);
      bkt[(h * NMOD + m) * CAP + pos] = b;
    }
  }
}

// ---- hop: per-module 64-row x 64-col tile, W staged in LDS ----------------
// grid: (m, slot, col-half) = 64*4*2 = 512 blocks
template <int HOP>
__global__ __launch_bounds__(256) void k_hop(const float* __restrict__ E,
                                             const int* __restrict__ eids,
                                             float* __restrict__ ws) {
  const int bx = blockIdx.x;
  const int m = bx >> 3, sl = (bx >> 1) & 3, ch = bx & 1;
  const int cn = ((const int*)(ws + OFF_CNT))[(HOP * NMOD + m) * CSTR];
  const int r0 = sl * 64;
  if (r0 >= cn) return;
  const int nr = min(64, cn - r0);
  const int c0 = ch * 64;

  __shared__ float wsm[64 * 64];  // [k-half][64 cols] 16 KB
  __shared__ float xs[64 * 129];  // [row][k] padded   33 KB
  __shared__ int rows[64];
  const int tid = threadIdx.x;
  const float* WT = ws + OFF_WT + (size_t)m * 16384;  // [k][o]
  const int* bkt = (const int*)(ws + OFF_BKT) + (HOP * NMOD + m) * CAP + r0;
  const float* Xprev = ws + (HOP == 1 ? OFF_X0 : OFF_X1);
  float* Xnext = ws + (HOP == 1 ? OFF_X1 : OFF_X0);

  if (tid < nr) rows[tid] = bkt[tid];
  __syncthreads();
  for (int e = tid; e < 64 * 32; e += 256) {
    const int row = e >> 5, i4 = e & 31;
    if (row < nr) {
      const int b = rows[row];
      const float* src = (HOP == 0) ? (E + (size_t)eids[b * 4] * EMB)
                                    : (Xprev + (size_t)b * EMB);
      *(float4*)&xs[row * 129 + 4 * i4] = *(const float4*)&src[4 * i4];
    }
  }

  const int tr = tid >> 4, tc = tid & 15;
  float acc[4][4] = {};
#pragma unroll
  for (int kh = 0; kh < 2; ++kh) {
    __syncthreads();  // xs ready (kh=0) / prev compute done (kh=1)
    for (int e = tid; e < 64 * 16; e += 256) {
      const int kk = e >> 4, c4 = e & 15;
      *(float4*)&wsm[kk * 64 + 4 * c4] =
          *(const float4*)&WT[(size_t)(kh * 64 + kk) * 128 + c0 + 4 * c4];
    }
    __syncthreads();
    const float* xk = xs + kh * 64;
#pragma unroll 4
    for (int kk = 0; kk < 64; ++kk) {
      const float4 bv = *(const float4*)&wsm[kk * 64 + tc * 4];
      const float a0 = xk[(tr * 4 + 0) * 129 + kk];
      const float a1 = xk[(tr * 4 + 1) * 129 + kk];
      const float a2 = xk[(tr * 4 + 2) * 129 + kk];
      const float a3 = xk[(tr * 4 + 3) * 129 + kk];
      acc[0][0] = fmaf(a0, bv.x, acc[0][0]); acc[0][1] = fmaf(a0, bv.y, acc[0][1]);
      acc[0][2] = fmaf(a0, bv.z, acc[0][2]); acc[0][3] = fmaf(a0, bv.w, acc[0][3]);
      acc[1][0] = fmaf(a1, bv.x, acc[1][0]); acc[1][1] = fmaf(a1, bv.y, acc[1][1]);
      acc[1][2] = fmaf(a1, bv.z, acc[1][2]); acc[1][3] = fmaf(a1, bv.w, acc[1][3]);
      acc[2][0] = fmaf(a2, bv.x, acc[2][0]); acc[2][1] = fmaf(a2, bv.y, acc[2][1]);
      acc[2][2] = fmaf(a2, bv.z, acc[2][2]); acc[2][3] = fmaf(a2, bv.w, acc[2][3]);
      acc[3][0] = fmaf(a3, bv.x, acc[3][0]); acc[3][1] = fmaf(a3, bv.y, acc[3][1]);
      acc[3][2] = fmaf(a3, bv.z, acc[3][2]); acc[3][3] = fmaf(a3, bv.w, acc[3][3]);
    }
  }

#pragma unroll
  for (int p = 0; p < 4; ++p) {
    const int row = tr * 4 + p;
    if (row < nr) {
      const int b = rows[row];
      const float4 bias =
          *(const float4*)&E[(size_t)eids[b * 4 + HOP + 1] * EMB + c0 + tc * 4];
      float4 o;
      o.x = fmaxf(acc[p][0] + bias.x, 0.f);
      o.y = fmaxf(acc[p][1] + bias.y, 0.f);
      o.z = fmaxf(acc[p][2] + bias.z, 0.f);
      o.w = fmaxf(acc[p][3] + bias.w, 0.f);
      if (HOP == 2) {
        o.x = (1.f - WB) * bias.x + WB * o.x;
        o.y = (1.f - WB) * bias.y + WB * o.y;
        o.z = (1.f - WB) * bias.z + WB * o.z;
        o.w = (1.f - WB) * bias.w + WB * o.w;
      }
      *(float4*)&Xnext[(size_t)b * EMB + c0 + tc * 4] = o;
    }
  }
}

// ---- fused MLP: 16 rows/block; H tile lives in LDS ------------------------
constexpr int HS = 516;  // H LDS stride (2-way max aliasing = free)
__global__ __launch_bounds__(256) void k_mlp(const float* __restrict__ b1,
                                             const float* __restrict__ b2,
                                             float* __restrict__ ws,
                                             float* __restrict__ out) {
  __shared__ float xs[16 * 129];    //  8.25 KB
  __shared__ float hs[16 * HS];     // 33.0 KB
  __shared__ float part[4 * 1024];  // 16.4 KB
  const int tid = threadIdx.x;
  const int row0 = blockIdx.x * 16;
  const float* X = ws + OFF_X0;
  const float* W1T = ws + OFF_W1T;
  const float* W2T = ws + OFF_W2T;

  for (int e = tid; e < 16 * 32; e += 256) {
    const int row = e >> 5, i4 = e & 31;
    *(float4*)&xs[row * 129 + 4 * i4] =
        *(const float4*)&X[(size_t)(row0 + row) * EMB + 4 * i4];
  }
  __syncthreads();

  const int wv = tid >> 6, ln = tid & 63;
#pragma unroll
  for (int pass = 0; pass < 2; ++pass) {
    float acc[4][4] = {};
    const float* Wp = W1T + pass * 256 + 4 * ln;
#pragma unroll 4
    for (int k = 0; k < 128; ++k) {
      const float4 w = *(const float4*)&Wp[(size_t)k * 512];
      const float a0 = xs[(wv * 4 + 0) * 129 + k];
      const float a1 = xs[(wv * 4 + 1) * 129 + k];
      const float a2 = xs[(wv * 4 + 2) * 129 + k];
      const float a3 = xs[(wv * 4 + 3) * 129 + k];
      acc[0][0] = fmaf(a0, w.x, acc[0][0]); acc[0][1] = fmaf(a0, w.y, acc[0][1]);
      acc[0][2] = fmaf(a0, w.z, acc[0][2]); acc[0][3] = fmaf(a0, w.w, acc[0][3]);
      acc[1][0] = fmaf(a1, w.x, acc[1][0]); acc[1][1] = fmaf(a1, w.y, acc[1][1]);
      acc[1][2] = fmaf(a1, w.z, acc[1][2]); acc[1][3] = fmaf(a1, w.w, acc[1][3]);
      acc[2][0] = fmaf(a2, w.x, acc[2][0]); acc[2][1] = fmaf(a2, w.y, acc[2][1]);
      acc[2][2] = fmaf(a2, w.z, acc[2][2]); acc[2][3] = fmaf(a2, w.w, acc[2][3]);
      acc[3][0] = fmaf(a3, w.x, acc[3][0]); acc[3][1] = fmaf(a3, w.y, acc[3][1]);
      acc[3][2] = fmaf(a3, w.z, acc[3][2]); acc[3][3] = fmaf(a3, w.w, acc[3][3]);
    }
    const float4 bb = *(const float4*)&b1[pass * 256 + 4 * ln];
#pragma unroll
    for (int r = 0; r < 4; ++r) {
      float4 o;
      o.x = fmaxf(acc[r][0] + bb.x, 0.f);
      o.y = fmaxf(acc[r][1] + bb.y, 0.f);
      o.z = fmaxf(acc[r][2] + bb.z, 0.f);
      o.w = fmaxf(acc[r][3] + bb.w, 0.f);
      *(float4*)&hs[(wv * 4 + r) * HS + pass * 256 + 4 * ln] = o;
    }
  }
  __syncthreads();

  // phase B: wave wv handles k in [wv*128, wv*128+128)
  const int lr = ln >> 4, lc = ln & 15;
  float acc2[4][4] = {};
  const float* W2p = W2T + (size_t)wv * 128 * 64 + 4 * lc;
#pragma unroll 4
  for (int kk = 0; kk < 128; ++kk) {
    const int k = wv * 128 + kk;
    const float4 w = *(const float4*)&W2p[(size_t)kk * 64];
    const float a0 = hs[(lr * 4 + 0) * HS + k];
    const float a1 = hs[(lr * 4 + 1) * HS + k];
    const float a2 = hs[(lr * 4 + 2) * HS + k];
    const float a3 = hs[(lr * 4 + 3) * HS + k];
    acc2[0][0] = fmaf(a0, w.x, acc2[0][0]); acc2[0][1] = fmaf(a0, w.y, acc2[0][1]);
    acc2[0][2] = fmaf(a0, w.z, acc2[0][2]); acc2[0][3] = fmaf(a0, w.w, acc2[0][3]);
    acc2[1][0] = fmaf(a1, w.x, acc2[1][0]); acc2[1][1] = fmaf(a1, w.y, acc2[1][1]);
    acc2[1][2] = fmaf(a1, w.z, acc2[1][2]); acc2[1][3] = fmaf(a1, w.w, acc2[1][3]);
    acc2[2][0] = fmaf(a2, w.x, acc2[2][0]); acc2[2][1] = fmaf(a2, w.y, acc2[2][1]);
    acc2[2][2] = fmaf(a2, w.z, acc2[2][2]); acc2[2][3] = fmaf(a2, w.w, acc2[2][3]);
    acc2[3][0] = fmaf(a3, w.x, acc2[3][0]); acc2[3][1] = fmaf(a3, w.y, acc2[3][1]);
    acc2[3][2] = fmaf(a3, w.z, acc2[3][2]); acc2[3][3] = fmaf(a3, w.w, acc2[3][3]);
  }
#pragma unroll
  for (int r = 0; r < 4; ++r) {
    float4 pv;
    pv.x = acc2[r][0]; pv.y = acc2[r][1]; pv.z = acc2[r][2]; pv.w = acc2[r][3];
    *(float4*)&part[wv * 1024 + (lr * 4 + r) * 64 + 4 * lc] = pv;
  }
  __syncthreads();

  {
    const int r = tid >> 4, cf = tid & 15;
    float4 s = *(const float4*)&part[r * 64 + 4 * cf];
#pragma unroll
    for (int w = 1; w < 4; ++w) {
      const float4 t = *(const float4*)&part[w * 1024 + r * 64 + 4 * cf];
      s.x += t.x; s.y += t.y; s.z += t.z; s.w += t.w;
    }
    const float4 bb = *(const float4*)&b2[4 * cf];
    float4 o;
    o.x = s.x + bb.x; o.y = s.y + bb.y; o.z = s.z + bb.z; o.w = s.w + bb.w;
    *(float4*)&out[(size_t)(row0 + r) * 64 + 4 * cf] = o;
  }
}

}  // namespace

extern "C" void kernel_launch(void* const* d_in, const int* in_sizes, int n_in,
                              void* d_out, int out_size, void* d_ws,
                              size_t ws_size, hipStream_t stream) {
  const float* E  = (const float*)d_in[0];
  const float* Wm = (const float*)d_in[1];
  const float* W1 = (const float*)d_in[2];
  const float* b1 = (const float*)d_in[3];
  const float* W2 = (const float*)d_in[4];
  const float* b2 = (const float*)d_in[5];
  const int* eids = (const int*)d_in[6];
  const int* mids = (const int*)d_in[7];
  float* out = (float*)d_out;
  float* ws = (float*)d_ws;

  (void)hipMemsetAsync((char*)d_ws + OFF_CNT * sizeof(float), 0,
                       192 * CSTR * sizeof(int), stream);
  k_prep<<<dim3(240), dim3(256), 0, stream>>>(Wm, W1, W2, mids, ws);
  k_hop<0><<<dim3(512), dim3(256), 0, stream>>>(E, eids, ws);
  k_hop<1><<<dim3(512), dim3(256), 0, stream>>>(E, eids, ws);
  k_hop<2><<<dim3(512), dim3(256), 0, stream>>>(E, eids, ws);
  k_mlp<<<dim3(512), dim3(256), 0, stream>>>(b1, b2, ws, out);
}

// Round 8
// 88.124 us; speedup vs baseline: 1.7518x; 1.2005x over previous
//
#include <hip/hip_runtime.h>

namespace {

typedef short bf16x8 __attribute__((ext_vector_type(8)));
typedef float f32x4 __attribute__((ext_vector_type(4)));

constexpr int BATCH = 8192;
constexpr int NMOD  = 64;
constexpr int CAP   = 256;   // Bin(8192,1/64) max ~170 << 256 (validated r1-r7)
constexpr int CSTR  = 16;    // counter stride in ints = 64B
constexpr float WB  = 1.0f / (7.0f * 0.5f);  // 2/7

// ws layout (float offsets)
constexpr size_t OFF_WHI = 0;                  // ushort[64*128*128] W_mods hi
constexpr size_t OFF_WLO = 524288;             // ushort[64*128*128] W_mods lo
constexpr size_t OFF_X0  = 1048576;            // 8192*128 f32
constexpr size_t OFF_X1  = 2097152;            // 8192*128 f32
constexpr size_t OFF_W1T = 3145728;            // 128*512  f32 [k][col]
constexpr size_t OFF_W2T = 3211264;            // 512*64   f32 [k][col]
constexpr size_t OFF_CNT = 3244032;            // 192*CSTR ints (zeroed)
constexpr size_t OFF_BKT = 3247104;            // 3*64*CAP ints
// end ~13.2 MB << ws_size

__device__ __forceinline__ ushort f2bf(float x) {  // RTN-even f32->bf16 bits
  unsigned u = __builtin_bit_cast(unsigned, x);
  u += 0x7FFFu + ((u >> 16) & 1u);
  return (ushort)(u >> 16);
}
__device__ __forceinline__ float bf2f(ushort h) {
  return __builtin_bit_cast(float, ((unsigned)h) << 16);
}
__device__ __forceinline__ void cvt8(const float* v, bf16x8& hi, bf16x8& lo) {
#pragma unroll
  for (int j = 0; j < 8; ++j) {
    const float x = v[j];
    const ushort h = f2bf(x);
    hi[j] = (short)h;
    lo[j] = (short)f2bf(x - bf2f(h));
  }
}

// ---- prep: Wm->bf16 hi/lo, W1T/W2T transposes, bucket scatter --------------
// bx 0..511: Wm conversion; 512..519: W1T; 520..527: W2T; 528..623: scatter
__global__ __launch_bounds__(256) void k_prep(const float* __restrict__ Wm,
                                              const float* __restrict__ W1,
                                              const float* __restrict__ W2,
                                              const int* __restrict__ mids,
                                              float* __restrict__ ws) {
  __shared__ float t[64 * 129];
  const int bx = blockIdx.x;
  const int tid = threadIdx.x;
  if (bx < 512) {  // W_mods f32 -> Whi/Wlo bf16 (layout unchanged [m][o][i])
    const size_t i8 = (size_t)bx * 256 + tid;  // 131072 threads x 8 elems
    float v[8];
    *(float4*)&v[0] = *(const float4*)&Wm[i8 * 8];
    *(float4*)&v[4] = *(const float4*)&Wm[i8 * 8 + 4];
    bf16x8 hi, lo;
    cvt8(v, hi, lo);
    *(bf16x8*)((ushort*)(ws + OFF_WHI) + i8 * 8) = hi;
    *(bf16x8*)((ushort*)(ws + OFF_WLO) + i8 * 8) = lo;
  } else if (bx < 520) {  // W1 [512][128] -> W1T [128][512]
    const int j = bx - 512;
    for (int e = tid; e < 64 * 32; e += 256) {
      const int r = e >> 5, i4 = e & 31;
      const float4 v = *(const float4*)&W1[(size_t)(j * 64 + r) * 128 + 4 * i4];
      float* d = &t[r * 129 + 4 * i4];
      d[0] = v.x; d[1] = v.y; d[2] = v.z; d[3] = v.w;
    }
    __syncthreads();
    float* W1T = ws + OFF_W1T;
    for (int e = tid; e < 128 * 16; e += 256) {
      const int i = e >> 4, r4 = e & 15;
      float4 v;
      v.x = t[(4 * r4 + 0) * 129 + i];
      v.y = t[(4 * r4 + 1) * 129 + i];
      v.z = t[(4 * r4 + 2) * 129 + i];
      v.w = t[(4 * r4 + 3) * 129 + i];
      *(float4*)&W1T[(size_t)i * 512 + j * 64 + 4 * r4] = v;
    }
  } else if (bx < 528) {  // W2 [64][512] -> W2T [512][64]
    const int j = bx - 520;
    float* t2 = t;  // [64][65]
    for (int e = tid; e < 64 * 16; e += 256) {
      const int o = e >> 4, k4 = e & 15;
      const float4 v = *(const float4*)&W2[(size_t)o * 512 + j * 64 + 4 * k4];
      float* d = &t2[o * 65 + 4 * k4];
      d[0] = v.x; d[1] = v.y; d[2] = v.z; d[3] = v.w;
    }
    __syncthreads();
    float* W2T = ws + OFF_W2T;
    for (int e = tid; e < 64 * 16; e += 256) {
      const int k = e >> 4, o4 = e & 15;
      float4 v;
      v.x = t2[(4 * o4 + 0) * 65 + k];
      v.y = t2[(4 * o4 + 1) * 65 + k];
      v.z = t2[(4 * o4 + 2) * 65 + k];
      v.w = t2[(4 * o4 + 3) * 65 + k];
      *(float4*)&W2T[(size_t)(j * 64 + k) * 64 + 4 * o4] = v;
    }
  } else {  // bucket scatter; padded counters
    const int idx = (bx - 528) * 256 + tid;
    if (idx < BATCH * 3) {
      const int b = idx / 3, h = idx - b * 3;
      const int m = mids[idx];
      int* cnt = (int*)(ws + OFF_CNT);
      int* bkt = (int*)(ws + OFF_BKT);
      const int pos = atomicAdd(&cnt[(h * NMOD + m) * CSTR], 1);
      bkt[(h * NMOD + m) * CAP + pos] = b;
    }
  }
}

// ---- hop: per-module 64x128 tile via MFMA bf16x3 --------------------------
// grid (m, slot) = 256 blocks; 4 waves: wave w = rowgroups (w&1)*2+{0,1} (16
// rows each) x colfrags (w>>1)*4+{0..3} (16 cols each). W staged in LDS as
// [col][k] bf16 hi/lo in two k-phases of 64 (stride 72 shorts: 2-way banks,
// 16B aligned). A-frags built in-register from gathered x rows.
template <int HOP>
__global__ __launch_bounds__(256, 2) void k_hop(const float* __restrict__ E,
                                                const int* __restrict__ eids,
                                                float* __restrict__ ws) {
  const int m = blockIdx.x >> 2, sl = blockIdx.x & 3;
  const int cn = ((const int*)(ws + OFF_CNT))[(HOP * NMOD + m) * CSTR];
  const int r0 = sl * 64;
  if (r0 >= cn) return;
  const int nr = min(64, cn - r0);

  __shared__ ushort wh[128 * 72];  // 18 KB
  __shared__ ushort wl[128 * 72];  // 18 KB
  __shared__ int rows[64], esrc[64], ebia[64];

  const int tid = threadIdx.x;
  const ushort* WhiG = (const ushort*)(ws + OFF_WHI) + (size_t)m * 16384;
  const ushort* WloG = (const ushort*)(ws + OFF_WLO) + (size_t)m * 16384;
  const int* bkt = (const int*)(ws + OFF_BKT) + (HOP * NMOD + m) * CAP + r0;
  const float* Xprev = ws + (HOP == 1 ? OFF_X0 : OFF_X1);
  float* Xnext = ws + (HOP == 1 ? OFF_X1 : OFF_X0);

  if (tid < 64) {
    const int b = bkt[tid < nr ? tid : 0];
    rows[tid] = b;
    esrc[tid] = (HOP == 0) ? eids[b * 4] : b;
    ebia[tid] = eids[b * 4 + HOP + 1];
  }

  const int w = tid >> 6, l = tid & 63;
  const int lg = l >> 4, lr = l & 15;      // k-group / row-or-col within frag
  const int g0 = (w & 1) * 2, f0 = (w >> 1) * 4;
  const float* xbase = (HOP == 0) ? E : Xprev;

  f32x4 acc[2][4] = {};

#pragma unroll
  for (int p = 0; p < 2; ++p) {
    __syncthreads();  // rows ready (p=0) / prev phase reads done (p=1)
    for (int e = tid; e < 128 * 8; e += 256) {
      const int c = e >> 3, s = e & 7;
      *(bf16x8*)&wh[c * 72 + s * 8] =
          *(const bf16x8*)&WhiG[(size_t)c * 128 + p * 64 + s * 8];
      *(bf16x8*)&wl[c * 72 + s * 8] =
          *(const bf16x8*)&WloG[(size_t)c * 128 + p * 64 + s * 8];
    }
    __syncthreads();

    // A fragments for this k-phase (2 rowgroups x 2 k-steps)
    bf16x8 ah[2][2], al[2][2];
#pragma unroll
    for (int g = 0; g < 2; ++g) {
      const int row = (g0 + g) * 16 + lr;
      const float* sp = xbase + (size_t)esrc[row] * 128;
#pragma unroll
      for (int s = 0; s < 2; ++s) {
        float v[8];
        const int k0 = p * 64 + s * 32 + lg * 8;
        *(float4*)&v[0] = *(const float4*)&sp[k0];
        *(float4*)&v[4] = *(const float4*)&sp[k0 + 4];
        cvt8(v, ah[g][s], al[g][s]);
      }
    }

#pragma unroll
    for (int f = 0; f < 4; ++f) {
      const int c = (f0 + f) * 16 + lr;
      bf16x8 bh[2], bl[2];
#pragma unroll
      for (int s = 0; s < 2; ++s) {
        bh[s] = *(const bf16x8*)&wh[c * 72 + s * 32 + lg * 8];
        bl[s] = *(const bf16x8*)&wl[c * 72 + s * 32 + lg * 8];
      }
#pragma unroll
      for (int g = 0; g < 2; ++g) {
#pragma unroll
        for (int s = 0; s < 2; ++s) {
          acc[g][f] = __builtin_amdgcn_mfma_f32_16x16x32_bf16(
              ah[g][s], bh[s], acc[g][f], 0, 0, 0);
          acc[g][f] = __builtin_amdgcn_mfma_f32_16x16x32_bf16(
              al[g][s], bh[s], acc[g][f], 0, 0, 0);
          acc[g][f] = __builtin_amdgcn_mfma_f32_16x16x32_bf16(
              ah[g][s], bl[s], acc[g][f], 0, 0, 0);
        }
      }
    }
  }

  // epilogue: C/D layout col=lane&15, row=(lane>>4)*4+q (m89-verified)
#pragma unroll
  for (int g = 0; g < 2; ++g) {
#pragma unroll
    for (int q = 0; q < 4; ++q) {
      const int row = (g0 + g) * 16 + lg * 4 + q;
      if (row < nr) {
        const int b = rows[row];
        const float* bp = E + (size_t)ebia[row] * 128;
        float* op = Xnext + (size_t)b * 128;
#pragma unroll
        for (int f = 0; f < 4; ++f) {
          const int col = (f0 + f) * 16 + lr;
          const float bias = bp[col];
          float v = fmaxf(acc[g][f][q] + bias, 0.f);
          if (HOP == 2) v = (1.f - WB) * bias + WB * v;
          op[col] = v;
        }
      }
    }
  }
}

// ---- fused MLP: 16 rows/block; H tile lives in LDS (unchanged from R7) ----
constexpr int HS = 516;
__global__ __launch_bounds__(256) void k_mlp(const float* __restrict__ b1,
                                             const float* __restrict__ b2,
                                             float* __restrict__ ws,
                                             float* __restrict__ out) {
  __shared__ float xs[16 * 129];
  __shared__ float hs[16 * HS];
  __shared__ float part[4 * 1024];
  const int tid = threadIdx.x;
  const int row0 = blockIdx.x * 16;
  const float* X = ws + OFF_X0;
  const float* W1T = ws + OFF_W1T;
  const float* W2T = ws + OFF_W2T;

  for (int e = tid; e < 16 * 32; e += 256) {
    const int row = e >> 5, i4 = e & 31;
    *(float4*)&xs[row * 129 + 4 * i4] =
        *(const float4*)&X[(size_t)(row0 + row) * 128 + 4 * i4];
  }
  __syncthreads();

  const int wv = tid >> 6, ln = tid & 63;
#pragma unroll
  for (int pass = 0; pass < 2; ++pass) {
    float acc[4][4] = {};
    const float* Wp = W1T + pass * 256 + 4 * ln;
#pragma unroll 4
    for (int k = 0; k < 128; ++k) {
      const float4 w = *(const float4*)&Wp[(size_t)k * 512];
      const float a0 = xs[(wv * 4 + 0) * 129 + k];
      const float a1 = xs[(wv * 4 + 1) * 129 + k];
      const float a2 = xs[(wv * 4 + 2) * 129 + k];
      const float a3 = xs[(wv * 4 + 3) * 129 + k];
      acc[0][0] = fmaf(a0, w.x, acc[0][0]); acc[0][1] = fmaf(a0, w.y, acc[0][1]);
      acc[0][2] = fmaf(a0, w.z, acc[0][2]); acc[0][3] = fmaf(a0, w.w, acc[0][3]);
      acc[1][0] = fmaf(a1, w.x, acc[1][0]); acc[1][1] = fmaf(a1, w.y, acc[1][1]);
      acc[1][2] = fmaf(a1, w.z, acc[1][2]); acc[1][3] = fmaf(a1, w.w, acc[1][3]);
      acc[2][0] = fmaf(a2, w.x, acc[2][0]); acc[2][1] = fmaf(a2, w.y, acc[2][1]);
      acc[2][2] = fmaf(a2, w.z, acc[2][2]); acc[2][3] = fmaf(a2, w.w, acc[2][3]);
      acc[3][0] = fmaf(a3, w.x, acc[3][0]); acc[3][1] = fmaf(a3, w.y, acc[3][1]);
      acc[3][2] = fmaf(a3, w.z, acc[3][2]); acc[3][3] = fmaf(a3, w.w, acc[3][3]);
    }
    const float4 bb = *(const float4*)&b1[pass * 256 + 4 * ln];
#pragma unroll
    for (int r = 0; r < 4; ++r) {
      float4 o;
      o.x = fmaxf(acc[r][0] + bb.x, 0.f);
      o.y = fmaxf(acc[r][1] + bb.y, 0.f);
      o.z = fmaxf(acc[r][2] + bb.z, 0.f);
      o.w = fmaxf(acc[r][3] + bb.w, 0.f);
      *(float4*)&hs[(wv * 4 + r) * HS + pass * 256 + 4 * ln] = o;
    }
  }
  __syncthreads();

  const int lr = ln >> 4, lc = ln & 15;
  float acc2[4][4] = {};
  const float* W2p = W2T + (size_t)wv * 128 * 64 + 4 * lc;
#pragma unroll 4
  for (int kk = 0; kk < 128; ++kk) {
    const int k = wv * 128 + kk;
    const float4 w = *(const float4*)&W2p[(size_t)kk * 64];
    const float a0 = hs[(lr * 4 + 0) * HS + k];
    const float a1 = hs[(lr * 4 + 1) * HS + k];
    const float a2 = hs[(lr * 4 + 2) * HS + k];
    const float a3 = hs[(lr * 4 + 3) * HS + k];
    acc2[0][0] = fmaf(a0, w.x, acc2[0][0]); acc2[0][1] = fmaf(a0, w.y, acc2[0][1]);
    acc2[0][2] = fmaf(a0, w.z, acc2[0][2]); acc2[0][3] = fmaf(a0, w.w, acc2[0][3]);
    acc2[1][0] = fmaf(a1, w.x, acc2[1][0]); acc2[1][1] = fmaf(a1, w.y, acc2[1][1]);
    acc2[1][2] = fmaf(a1, w.z, acc2[1][2]); acc2[1][3] = fmaf(a1, w.w, acc2[1][3]);
    acc2[2][0] = fmaf(a2, w.x, acc2[2][0]); acc2[2][1] = fmaf(a2, w.y, acc2[2][1]);
    acc2[2][2] = fmaf(a2, w.z, acc2[2][2]); acc2[2][3] = fmaf(a2, w.w, acc2[2][3]);
    acc2[3][0] = fmaf(a3, w.x, acc2[3][0]); acc2[3][1] = fmaf(a3, w.y, acc2[3][1]);
    acc2[3][2] = fmaf(a3, w.z, acc2[3][2]); acc2[3][3] = fmaf(a3, w.w, acc2[3][3]);
  }
#pragma unroll
  for (int r = 0; r < 4; ++r) {
    float4 pv;
    pv.x = acc2[r][0]; pv.y = acc2[r][1]; pv.z = acc2[r][2]; pv.w = acc2[r][3];
    *(float4*)&part[wv * 1024 + (lr * 4 + r) * 64 + 4 * lc] = pv;
  }
  __syncthreads();

  {
    const int r = tid >> 4, cf = tid & 15;
    float4 s = *(const float4*)&part[r * 64 + 4 * cf];
#pragma unroll
    for (int w = 1; w < 4; ++w) {
      const float4 t2 = *(const float4*)&part[w * 1024 + r * 64 + 4 * cf];
      s.x += t2.x; s.y += t2.y; s.z += t2.z; s.w += t2.w;
    }
    const float4 bb = *(const float4*)&b2[4 * cf];
    float4 o;
    o.x = s.x + bb.x; o.y = s.y + bb.y; o.z = s.z + bb.z; o.w = s.w + bb.w;
    *(float4*)&out[(size_t)(row0 + r) * 64 + 4 * cf] = o;
  }
}

}  // namespace

extern "C" void kernel_launch(void* const* d_in, const int* in_sizes, int n_in,
                              void* d_out, int out_size, void* d_ws,
                              size_t ws_size, hipStream_t stream) {
  const float* E  = (const float*)d_in[0];
  const float* Wm = (const float*)d_in[1];
  const float* W1 = (const float*)d_in[2];
  const float* b1 = (const float*)d_in[3];
  const float* W2 = (const float*)d_in[4];
  const float* b2 = (const float*)d_in[5];
  const int* eids = (const int*)d_in[6];
  const int* mids = (const int*)d_in[7];
  float* out = (float*)d_out;
  float* ws = (float*)d_ws;

  (void)hipMemsetAsync((char*)d_ws + OFF_CNT * sizeof(float), 0,
                       192 * CSTR * sizeof(int), stream);
  k_prep<<<dim3(624), dim3(256), 0, stream>>>(Wm, W1, W2, mids, ws);
  k_hop<0><<<dim3(256), dim3(256), 0, stream>>>(E, eids, ws);
  k_hop<1><<<dim3(256), dim3(256), 0, stream>>>(E, eids, ws);
  k_hop<2><<<dim3(256), dim3(256), 0, stream>>>(E, eids, ws);
  k_mlp<<<dim3(512), dim3(256), 0, stream>>>(b1, b2, ws, out);
}

// Round 9
// 80.185 us; speedup vs baseline: 1.9253x; 1.0990x over previous
//
#include <hip/hip_runtime.h>

namespace {

typedef short bf16x8 __attribute__((ext_vector_type(8)));
typedef float f32x4 __attribute__((ext_vector_type(4)));

constexpr int BATCH = 8192;
constexpr int NMOD  = 64;
constexpr int CAP   = 256;   // Bin(8192,1/64) max ~170 << 256 (validated r1-r8)
constexpr int CSTR  = 16;    // counter stride in ints = 64B
constexpr float WB  = 1.0f / (7.0f * 0.5f);  // 2/7

// ws layout (float offsets)
constexpr size_t OFF_WHI = 0;                  // ushort[64*128*128] Wm hi [m][o][i]
constexpr size_t OFF_WLO = 524288;             // ushort[64*128*128] Wm lo
constexpr size_t OFF_XH0 = 1048576;            // ushort[8192*128] X0 hi
constexpr size_t OFF_XL0 = 1572864;            // ushort[8192*128] X0 lo
constexpr size_t OFF_XH1 = 2097152;            // ushort[8192*128] X1 hi
constexpr size_t OFF_XL1 = 2621440;            // ushort[8192*128] X1 lo
constexpr size_t OFF_W1H = 3145728;            // ushort[512*128] W1 hi [col][k]
constexpr size_t OFF_W1L = 3178496;            // ushort[512*128] W1 lo
constexpr size_t OFF_W2H = 3211264;            // ushort[64*512]  W2 hi [o][k]
constexpr size_t OFF_W2L = 3227648;            // ushort[64*512]  W2 lo
constexpr size_t OFF_CNT = 3244032;            // 192*CSTR ints (zeroed)
constexpr size_t OFF_BKT = 3247104;            // 3*64*CAP ints
// end ~13.2 MB << ws_size

__device__ __forceinline__ ushort f2bf(float x) {  // RTN-even f32->bf16 bits
  unsigned u = __builtin_bit_cast(unsigned, x);
  u += 0x7FFFu + ((u >> 16) & 1u);
  return (ushort)(u >> 16);
}
__device__ __forceinline__ float bf2f(ushort h) {
  return __builtin_bit_cast(float, ((unsigned)h) << 16);
}
__device__ __forceinline__ void cvt8(const float* v, bf16x8& hi, bf16x8& lo) {
#pragma unroll
  for (int j = 0; j < 8; ++j) {
    const float x = v[j];
    const ushort h = f2bf(x);
    hi[j] = (short)h;
    lo[j] = (short)f2bf(x - bf2f(h));
  }
}

// ---- prep: hi/lo conversions (no transposes needed!) + bucket scatter -----
// bx 0..511: Wm; 512..543: W1; 544..559: W2; 560..655: scatter
__global__ __launch_bounds__(256) void k_prep(const float* __restrict__ Wm,
                                              const float* __restrict__ W1,
                                              const float* __restrict__ W2,
                                              const int* __restrict__ mids,
                                              float* __restrict__ ws) {
  const int bx = blockIdx.x;
  const int tid = threadIdx.x;
  if (bx < 560) {  // elementwise f32 -> bf16 hi/lo, layout preserved
    const float* src;
    ushort *dh, *dl;
    size_t i8;
    if (bx < 512) {
      src = Wm; dh = (ushort*)(ws + OFF_WHI); dl = (ushort*)(ws + OFF_WLO);
      i8 = (size_t)bx * 256 + tid;
    } else if (bx < 544) {
      src = W1; dh = (ushort*)(ws + OFF_W1H); dl = (ushort*)(ws + OFF_W1L);
      i8 = (size_t)(bx - 512) * 256 + tid;
    } else {
      src = W2; dh = (ushort*)(ws + OFF_W2H); dl = (ushort*)(ws + OFF_W2L);
      i8 = (size_t)(bx - 544) * 256 + tid;
    }
    float v[8];
    *(float4*)&v[0] = *(const float4*)&src[i8 * 8];
    *(float4*)&v[4] = *(const float4*)&src[i8 * 8 + 4];
    bf16x8 hi, lo;
    cvt8(v, hi, lo);
    *(bf16x8*)&dh[i8 * 8] = hi;
    *(bf16x8*)&dl[i8 * 8] = lo;
  } else {  // bucket scatter; padded counters
    const int idx = (bx - 560) * 256 + tid;
    if (idx < BATCH * 3) {
      const int b = idx / 3, h = idx - b * 3;
      const int m = mids[idx];
      int* cnt = (int*)(ws + OFF_CNT);
      int* bkt = (int*)(ws + OFF_BKT);
      const int pos = atomicAdd(&cnt[(h * NMOD + m) * CSTR], 1);
      bkt[(h * NMOD + m) * CAP + pos] = b;
    }
  }
}

// ---- hop: per-module 64x128 tile via MFMA bf16x3 --------------------------
// X intermediates are bf16 hi/lo; hop0 gathers E (f32) + cvt.
template <int HOP>
__global__ __launch_bounds__(256, 2) void k_hop(const float* __restrict__ E,
                                                const int* __restrict__ eids,
                                                float* __restrict__ ws) {
  const int m = blockIdx.x >> 2, sl = blockIdx.x & 3;
  const int cn = ((const int*)(ws + OFF_CNT))[(HOP * NMOD + m) * CSTR];
  const int r0 = sl * 64;
  if (r0 >= cn) return;
  const int nr = min(64, cn - r0);

  __shared__ ushort wh[128 * 72];  // 18 KB
  __shared__ ushort wl[128 * 72];  // 18 KB
  __shared__ int rows[64], esrc[64], ebia[64];

  const int tid = threadIdx.x;
  const ushort* WhiG = (const ushort*)(ws + OFF_WHI) + (size_t)m * 16384;
  const ushort* WloG = (const ushort*)(ws + OFF_WLO) + (size_t)m * 16384;
  const int* bkt = (const int*)(ws + OFF_BKT) + (HOP * NMOD + m) * CAP + r0;
  const ushort* XHp = (const ushort*)(ws + (HOP == 2 ? OFF_XH1 : OFF_XH0));
  const ushort* XLp = (const ushort*)(ws + (HOP == 2 ? OFF_XL1 : OFF_XL0));
  ushort* XHn = (ushort*)(ws + (HOP == 1 ? OFF_XH1 : OFF_XH0));
  ushort* XLn = (ushort*)(ws + (HOP == 1 ? OFF_XL1 : OFF_XL0));

  if (tid < 64) {
    const int b = bkt[tid < nr ? tid : 0];
    rows[tid] = b;
    esrc[tid] = (HOP == 0) ? eids[b * 4] : b;
    ebia[tid] = eids[b * 4 + HOP + 1];
  }

  const int w = tid >> 6, l = tid & 63;
  const int lg = l >> 4, lr = l & 15;
  const int g0 = (w & 1) * 2, f0 = (w >> 1) * 4;

  f32x4 acc[2][4] = {};

#pragma unroll
  for (int p = 0; p < 2; ++p) {
    __syncthreads();  // rows ready (p=0) / prev phase reads done (p=1)
    for (int e = tid; e < 128 * 8; e += 256) {
      const int c = e >> 3, s = e & 7;
      *(bf16x8*)&wh[c * 72 + s * 8] =
          *(const bf16x8*)&WhiG[(size_t)c * 128 + p * 64 + s * 8];
      *(bf16x8*)&wl[c * 72 + s * 8] =
          *(const bf16x8*)&WloG[(size_t)c * 128 + p * 64 + s * 8];
    }
    __syncthreads();

    bf16x8 ah[2][2], al[2][2];
#pragma unroll
    for (int g = 0; g < 2; ++g) {
      const int row = (g0 + g) * 16 + lr;
#pragma unroll
      for (int s = 0; s < 2; ++s) {
        const int k0 = p * 64 + s * 32 + lg * 8;
        if (HOP == 0) {
          const float* sp = E + (size_t)esrc[row] * 128;
          float v[8];
          *(float4*)&v[0] = *(const float4*)&sp[k0];
          *(float4*)&v[4] = *(const float4*)&sp[k0 + 4];
          cvt8(v, ah[g][s], al[g][s]);
        } else {
          const size_t xo = (size_t)esrc[row] * 128 + k0;
          ah[g][s] = *(const bf16x8*)&XHp[xo];
          al[g][s] = *(const bf16x8*)&XLp[xo];
        }
      }
    }

#pragma unroll
    for (int f = 0; f < 4; ++f) {
      const int c = (f0 + f) * 16 + lr;
      bf16x8 bh[2], bl[2];
#pragma unroll
      for (int s = 0; s < 2; ++s) {
        bh[s] = *(const bf16x8*)&wh[c * 72 + s * 32 + lg * 8];
        bl[s] = *(const bf16x8*)&wl[c * 72 + s * 32 + lg * 8];
      }
#pragma unroll
      for (int g = 0; g < 2; ++g) {
#pragma unroll
        for (int s = 0; s < 2; ++s) {
          acc[g][f] = __builtin_amdgcn_mfma_f32_16x16x32_bf16(
              ah[g][s], bh[s], acc[g][f], 0, 0, 0);
          acc[g][f] = __builtin_amdgcn_mfma_f32_16x16x32_bf16(
              al[g][s], bh[s], acc[g][f], 0, 0, 0);
          acc[g][f] = __builtin_amdgcn_mfma_f32_16x16x32_bf16(
              ah[g][s], bl[s], acc[g][f], 0, 0, 0);
        }
      }
    }
  }

  // epilogue: C/D col=lane&15, row=4*(lane>>4)+q (validated r8)
#pragma unroll
  for (int g = 0; g < 2; ++g) {
#pragma unroll
    for (int q = 0; q < 4; ++q) {
      const int row = (g0 + g) * 16 + lg * 4 + q;
      if (row < nr) {
        const int b = rows[row];
        const float* bp = E + (size_t)ebia[row] * 128;
        const size_t ob = (size_t)b * 128;
#pragma unroll
        for (int f = 0; f < 4; ++f) {
          const int col = (f0 + f) * 16 + lr;
          const float bias = bp[col];
          float v = fmaxf(acc[g][f][q] + bias, 0.f);
          if (HOP == 2) v = (1.f - WB) * bias + WB * v;
          const ushort h = f2bf(v);
          XHn[ob + col] = h;
          XLn[ob + col] = f2bf(v - bf2f(h));
        }
      }
    }
  }
}

// ---- fused MLP via MFMA bf16x3: 16 rows/block, 512 blocks -----------------
// phase A: H = relu(X @ W1^T + b1); wave w owns cols 128w..128w+127.
//   A = X (hi/lo from global), B = W1 [col][k] (hi/lo from L2).
//   H -> bf16 hi/lo in LDS [16][520] (16B-aligned rows).
// phase B: out^T trick: A = W2 [o][k], B = H^T (LDS); wave w owns o 16w..16w+15.
constexpr int HSTR = 520;
__global__ __launch_bounds__(256, 2) void k_mlp(const float* __restrict__ b1,
                                                const float* __restrict__ b2,
                                                float* __restrict__ ws,
                                                float* __restrict__ out) {
  __shared__ ushort hh[16 * HSTR];  // 16.25 KB
  __shared__ ushort hl[16 * HSTR];  // 16.25 KB
  const int tid = threadIdx.x;
  const int row0 = blockIdx.x * 16;
  const ushort* XH = (const ushort*)(ws + OFF_XH0);
  const ushort* XL = (const ushort*)(ws + OFF_XL0);
  const ushort* W1H = (const ushort*)(ws + OFF_W1H);
  const ushort* W1L = (const ushort*)(ws + OFF_W1L);
  const ushort* W2H = (const ushort*)(ws + OFF_W2H);
  const ushort* W2L = (const ushort*)(ws + OFF_W2L);

  const int w = tid >> 6, l = tid & 63;
  const int lg = l >> 4, lr = l & 15;

  // phase A
  bf16x8 ah[4], al[4];
#pragma unroll
  for (int s = 0; s < 4; ++s) {
    const size_t xo = (size_t)(row0 + lr) * 128 + s * 32 + lg * 8;
    ah[s] = *(const bf16x8*)&XH[xo];
    al[s] = *(const bf16x8*)&XL[xo];
  }
  f32x4 acc[8] = {};
#pragma unroll
  for (int f = 0; f < 8; ++f) {
    const int c = w * 128 + f * 16 + lr;
#pragma unroll
    for (int s = 0; s < 4; ++s) {
      const size_t wo = (size_t)c * 128 + s * 32 + lg * 8;
      const bf16x8 bh = *(const bf16x8*)&W1H[wo];
      const bf16x8 bl = *(const bf16x8*)&W1L[wo];
      acc[f] = __builtin_amdgcn_mfma_f32_16x16x32_bf16(ah[s], bh, acc[f], 0, 0, 0);
      acc[f] = __builtin_amdgcn_mfma_f32_16x16x32_bf16(al[s], bh, acc[f], 0, 0, 0);
      acc[f] = __builtin_amdgcn_mfma_f32_16x16x32_bf16(ah[s], bl, acc[f], 0, 0, 0);
    }
  }
#pragma unroll
  for (int f = 0; f < 8; ++f) {
    const int c = w * 128 + f * 16 + lr;
    const float bb = b1[c];
#pragma unroll
    for (int q = 0; q < 4; ++q) {
      const int r = lg * 4 + q;
      const float v = fmaxf(acc[f][q] + bb, 0.f);
      const ushort h = f2bf(v);
      hh[r * HSTR + c] = h;
      hl[r * HSTR + c] = f2bf(v - bf2f(h));
    }
  }
  __syncthreads();

  // phase B
  f32x4 acc2 = {};
#pragma unroll 4
  for (int s = 0; s < 16; ++s) {
    const size_t wo = (size_t)(w * 16 + lr) * 512 + s * 32 + lg * 8;
    const bf16x8 a2h = *(const bf16x8*)&W2H[wo];
    const bf16x8 a2l = *(const bf16x8*)&W2L[wo];
    const int ko = s * 32 + lg * 8;
    const bf16x8 b2h = *(const bf16x8*)&hh[lr * HSTR + ko];
    const bf16x8 b2l = *(const bf16x8*)&hl[lr * HSTR + ko];
    acc2 = __builtin_amdgcn_mfma_f32_16x16x32_bf16(a2h, b2h, acc2, 0, 0, 0);
    acc2 = __builtin_amdgcn_mfma_f32_16x16x32_bf16(a2l, b2h, acc2, 0, 0, 0);
    acc2 = __builtin_amdgcn_mfma_f32_16x16x32_bf16(a2h, b2l, acc2, 0, 0, 0);
  }
  // D: batch row = lane&15, o = 16w + 4*(lane>>4) + q (contiguous 4 -> float4)
  const float4 bb2 = *(const float4*)&b2[w * 16 + lg * 4];
  float4 o;
  o.x = acc2[0] + bb2.x;
  o.y = acc2[1] + bb2.y;
  o.z = acc2[2] + bb2.z;
  o.w = acc2[3] + bb2.w;
  *(float4*)&out[(size_t)(row0 + lr) * 64 + w * 16 + lg * 4] = o;
}

}  // namespace

extern "C" void kernel_launch(void* const* d_in, const int* in_sizes, int n_in,
                              void* d_out, int out_size, void* d_ws,
                              size_t ws_size, hipStream_t stream) {
  const float* E  = (const float*)d_in[0];
  const float* Wm = (const float*)d_in[1];
  const float* W1 = (const float*)d_in[2];
  const float* b1 = (const float*)d_in[3];
  const float* W2 = (const float*)d_in[4];
  const float* b2 = (const float*)d_in[5];
  const int* eids = (const int*)d_in[6];
  const int* mids = (const int*)d_in[7];
  float* out = (float*)d_out;
  float* ws = (float*)d_ws;

  (void)hipMemsetAsync((char*)d_ws + OFF_CNT * sizeof(float), 0,
                       192 * CSTR * sizeof(int), stream);
  k_prep<<<dim3(656), dim3(256), 0, stream>>>(Wm, W1, W2, mids, ws);
  k_hop<0><<<dim3(256), dim3(256), 0, stream>>>(E, eids, ws);
  k_hop<1><<<dim3(256), dim3(256), 0, stream>>>(E, eids, ws);
  k_hop<2><<<dim3(256), dim3(256), 0, stream>>>(E, eids, ws);
  k_mlp<<<dim3(512), dim3(256), 0, stream>>>(b1, b2, ws, out);
}